// Round 1
// baseline (2348.123 us; speedup 1.0000x reference)
//
#include <hip/hip_runtime.h>
#include <math.h>

#define Bb 4
#define Cc 256
#define Nn 4096
#define Dd 32

#define QT 64      // query tile
#define JT 64      // key tile
#define SPAD 68    // s_s row stride (floats): 16B-aligned rows, mod-32 = 4
#define CGRP 64    // channels per block
#define CPT 16     // channels per thread (CGRP / 4 ty-groups)

// ---------------------------------------------------------------------------
// Kernel A: QKV projection.  q[b,d,n] = sum_c qw[d,c] x[b,c,n]  (same for k,v)
// grid (Nn/1024, 20, B), block 256. Each thread: 4 consecutive n (float4),
// 16 output rows. blockIdx.y: 0-1 -> q rows, 2-3 -> k rows, 4-19 -> v rows.
// ---------------------------------------------------------------------------
__global__ void qkv_proj(const float* __restrict__ x,
                         const float* __restrict__ qw,
                         const float* __restrict__ kw,
                         const float* __restrict__ vw,
                         float* __restrict__ q_ws,
                         float* __restrict__ k_ws,
                         float* __restrict__ v_ws) {
    const int b  = blockIdx.z;
    const int o0 = blockIdx.y * 16;
    const int n0 = blockIdx.x * 1024 + threadIdx.x * 4;

    const float* wbase;
    float* dst;
    int orow;
    if (o0 < 32)      { wbase = qw; dst = q_ws + b * Dd * Nn; orow = o0;      }
    else if (o0 < 64) { wbase = kw; dst = k_ws + b * Dd * Nn; orow = o0 - 32; }
    else              { wbase = vw; dst = v_ws + b * Cc * Nn; orow = o0 - 64; }

    float4 acc[16];
#pragma unroll
    for (int o = 0; o < 16; ++o) acc[o] = make_float4(0.f, 0.f, 0.f, 0.f);

    const float* xb = x + b * Cc * Nn + n0;
    for (int c = 0; c < Cc; ++c) {
        float4 xv = *(const float4*)(xb + c * Nn);
#pragma unroll
        for (int o = 0; o < 16; ++o) {
            float w = wbase[(orow + o) * Cc + c];   // wave-uniform -> s_load
            acc[o].x += w * xv.x;
            acc[o].y += w * xv.y;
            acc[o].z += w * xv.z;
            acc[o].w += w * xv.w;
        }
    }
#pragma unroll
    for (int o = 0; o < 16; ++o)
        *(float4*)(dst + (orow + o) * Nn + n0) = acc[o];
}

// ---------------------------------------------------------------------------
// Kernel B: flash-style attention + epilogue  out = gamma*(PV/l) + x
// grid (Nn/QT, Cc/CGRP, B) = (64,4,4) = 1024 blocks, block 256.
// Thread (ty=tid/64, tx=tid&63): query i = tx, channels c = cg*64+ty*16+cc.
// ---------------------------------------------------------------------------
__global__ __launch_bounds__(256, 4)
void attn(const float* __restrict__ x,
          const float* __restrict__ q_ws,
          const float* __restrict__ k_ws,
          const float* __restrict__ v_ws,
          const float* __restrict__ gamma,
          float* __restrict__ out) {
    __shared__ float q_s[Dd][QT];        // 8 KB
    __shared__ float k_s[Dd][JT];        // 8 KB
    __shared__ float s_s[QT][SPAD];      // 17 KB  (S tile, then P tile)
    __shared__ float alpha_s[QT];
    __shared__ float l_s[QT];

    const int b   = blockIdx.z;
    const int cg  = blockIdx.y;
    const int i0  = blockIdx.x * QT;
    const int tid = threadIdx.x;
    const int tx  = tid & 63;
    const int ty  = tid >> 6;

    // stage q tile (coalesced: consecutive tid -> consecutive i)
    for (int r = tid; r < Dd * QT; r += 256) {
        int d = r >> 6, i = r & 63;
        q_s[d][i] = q_ws[(b * Dd + d) * Nn + i0 + i];
    }

    float o_acc[CPT];
#pragma unroll
    for (int cc = 0; cc < CPT; ++cc) o_acc[cc] = 0.f;

    float m_i = -1e30f, l_i = 0.f;   // row state, valid for tid<64 (row = tid)

    const float* vbase = v_ws + (b * Cc + cg * CGRP + ty * CPT) * Nn;
    const int jb = ty * 16;          // this thread's 16-column S segment

    for (int jt = 0; jt < Nn / JT; ++jt) {
        const int j0 = jt * JT;
        __syncthreads();             // prior PV reads of s_s / k_s done
        for (int r = tid; r < Dd * JT; r += 256) {
            int d = r >> 6, j = r & 63;
            k_s[d][j] = k_ws[(b * Dd + d) * Nn + j0 + j];
        }
        __syncthreads();

        // ---- S = q^T k : thread computes S[tx][jb..jb+15] ----
        {
            float4 a0 = make_float4(0.f,0.f,0.f,0.f), a1 = a0, a2 = a0, a3 = a0;
#pragma unroll 8
            for (int d = 0; d < Dd; ++d) {
                float qd = q_s[d][tx];                         // stride-1, free
                const float4* kr = (const float4*)&k_s[d][jb]; // wave-uniform -> bcast
                float4 k0 = kr[0], k1 = kr[1], k2 = kr[2], k3 = kr[3];
                a0.x += qd*k0.x; a0.y += qd*k0.y; a0.z += qd*k0.z; a0.w += qd*k0.w;
                a1.x += qd*k1.x; a1.y += qd*k1.y; a1.z += qd*k1.z; a1.w += qd*k1.w;
                a2.x += qd*k2.x; a2.y += qd*k2.y; a2.z += qd*k2.z; a2.w += qd*k2.w;
                a3.x += qd*k3.x; a3.y += qd*k3.y; a3.z += qd*k3.z; a3.w += qd*k3.w;
            }
            float4* srow = (float4*)&s_s[tx][jb];   // rows 16B-aligned (SPAD=68)
            srow[0] = a0; srow[1] = a1; srow[2] = a2; srow[3] = a3;
        }
        __syncthreads();

        // ---- online softmax over this tile: wave 0, one row per thread ----
        if (tid < QT) {
            float* row = s_s[tid];
            float tmax = row[0];
            for (int j = 1; j < JT; ++j) tmax = fmaxf(tmax, row[j]);
            float m_new = fmaxf(m_i, tmax);
            float alpha = __expf(m_i - m_new);
            float psum = 0.f;
            for (int j = 0; j < JT; ++j) {
                float p = __expf(row[j] - m_new);
                row[j] = p;
                psum += p;
            }
            l_i = alpha * l_i + psum;
            m_i = m_new;
            alpha_s[tid] = alpha;
        }
        __syncthreads();

        // ---- PV update: o[c][tx] = alpha*o + sum_j P[tx][j] v[c][j0+j] ----
        float alpha = alpha_s[tx];
#pragma unroll
        for (int cc = 0; cc < CPT; ++cc) o_acc[cc] *= alpha;

        const float* vj = vbase + j0;
        for (int j4 = 0; j4 < JT / 4; ++j4) {
            float4 p4 = *(const float4*)&s_s[tx][j4 * 4];
#pragma unroll
            for (int cc = 0; cc < CPT; ++cc) {
                float4 v4 = *(const float4*)(vj + cc * Nn + j4 * 4); // wave-uniform
                o_acc[cc] += p4.x * v4.x + p4.y * v4.y + p4.z * v4.z + p4.w * v4.w;
            }
        }
    }

    if (tid < QT) l_s[tid] = l_i;
    __syncthreads();

    const float linv = 1.0f / l_s[tx];
    const float g = gamma[0];
    const int cbase = cg * CGRP + ty * CPT;
    const float* xb = x   + (b * Cc + cbase) * Nn + i0 + tx;
    float*       ob = out + (b * Cc + cbase) * Nn + i0 + tx;
#pragma unroll
    for (int cc = 0; cc < CPT; ++cc)
        ob[cc * Nn] = g * (o_acc[cc] * linv) + xb[cc * Nn];
}

// ---------------------------------------------------------------------------
extern "C" void kernel_launch(void* const* d_in, const int* in_sizes, int n_in,
                              void* d_out, int out_size, void* d_ws, size_t ws_size,
                              hipStream_t stream) {
    const float* x     = (const float*)d_in[0];
    const float* qw    = (const float*)d_in[1];
    const float* kw    = (const float*)d_in[2];
    const float* vw    = (const float*)d_in[3];
    const float* gamma = (const float*)d_in[4];
    float* out = (float*)d_out;

    float* ws   = (float*)d_ws;
    float* q_ws = ws;                       // B*D*N floats  (2 MB)
    float* k_ws = ws + Bb * Dd * Nn;        // B*D*N floats  (2 MB)
    float* v_ws = ws + 2 * Bb * Dd * Nn;    // B*C*N floats  (16.8 MB)

    qkv_proj<<<dim3(Nn / 1024, 20, Bb), 256, 0, stream>>>(x, qw, kw, vw,
                                                          q_ws, k_ws, v_ws);
    attn<<<dim3(Nn / QT, Cc / CGRP, Bb), 256, 0, stream>>>(x, q_ws, k_ws, v_ws,
                                                           gamma, out);
}

// Round 2
// 253.120 us; speedup vs baseline: 9.2767x; 9.2767x over previous
//
#include <hip/hip_runtime.h>
#include <math.h>

#define Bb 4
#define Cc 256
#define Nn 4096
#define Dd 32
#define CH 128   // channels per attn block (2 channel-groups)

typedef __attribute__((ext_vector_type(8))) short bf16x8;
typedef __attribute__((ext_vector_type(4))) float f32x4;

__device__ __forceinline__ unsigned short f2bf(float x) {
    union { float f; unsigned u; } c; c.f = x;
    unsigned r = c.u + 0x7fffu + ((c.u >> 16) & 1u);   // RNE
    return (unsigned short)(r >> 16);
}
__device__ __forceinline__ unsigned pk2(float a, float b) {
    return (unsigned)f2bf(a) | ((unsigned)f2bf(b) << 16);
}
__device__ __forceinline__ void load_lds16(const void* g, void* l) {
    __builtin_amdgcn_global_load_lds(
        (const __attribute__((address_space(1))) void*)g,
        (__attribute__((address_space(3))) void*)l, 16, 0, 0);
}

// ---------------------------------------------------------------------------
// QKV projection -> bf16.  q_t/k_t stored TRANSPOSED: [b][n][32] (frag-friendly)
// v_b stored [b][c][n].  grid (4, 20, B), block 256, 16 out-rows per block.
// ---------------------------------------------------------------------------
__global__ __launch_bounds__(256) void qkv_proj(
    const float* __restrict__ x, const float* __restrict__ qw,
    const float* __restrict__ kw, const float* __restrict__ vw,
    short* __restrict__ q_t, short* __restrict__ k_t, short* __restrict__ v_b) {
    const int b = blockIdx.z, grp = blockIdx.y;
    const int n0 = blockIdx.x * 1024 + threadIdx.x * 4;

    const float* wbase; int orow, mode;
    if (grp < 2)       { wbase = qw; orow = grp * 16;       mode = 0; }
    else if (grp < 4)  { wbase = kw; orow = (grp - 2) * 16; mode = 1; }
    else               { wbase = vw; orow = (grp - 4) * 16; mode = 2; }

    float acc[16][4];
#pragma unroll
    for (int o = 0; o < 16; ++o)
#pragma unroll
        for (int cc = 0; cc < 4; ++cc) acc[o][cc] = 0.f;

    const float* xb = x + (size_t)b * Cc * Nn + n0;
    for (int c = 0; c < Cc; ++c) {
        const float4 xv = *(const float4*)(xb + (size_t)c * Nn);
        const float* wc = wbase + (size_t)orow * Cc + c;
#pragma unroll
        for (int o = 0; o < 16; ++o) {
            const float wv = wc[o * Cc];      // wave-uniform -> s_load
            acc[o][0] += wv * xv.x;
            acc[o][1] += wv * xv.y;
            acc[o][2] += wv * xv.z;
            acc[o][3] += wv * xv.w;
        }
    }

    if (mode < 2) {
        short* dst = (mode == 0 ? q_t : k_t) + (size_t)b * Nn * Dd;
#pragma unroll
        for (int nc = 0; nc < 4; ++nc) {
            unsigned u[8];
#pragma unroll
            for (int h = 0; h < 8; ++h) u[h] = pk2(acc[2*h][nc], acc[2*h+1][nc]);
            uint4* d0 = (uint4*)(dst + (size_t)(n0 + nc) * Dd + orow);
            d0[0] = make_uint4(u[0], u[1], u[2], u[3]);
            d0[1] = make_uint4(u[4], u[5], u[6], u[7]);
        }
    } else {
#pragma unroll
        for (int o = 0; o < 16; ++o) {
            uint2 pv = make_uint2(pk2(acc[o][0], acc[o][1]),
                                  pk2(acc[o][2], acc[o][3]));
            *(uint2*)(v_b + ((size_t)(b * Cc + orow + o)) * Nn + n0) = pv;
        }
    }
}

// ---------------------------------------------------------------------------
// Flash attention, bf16 MFMA 16x16x32.
// grid (Nn/64, Cc/CH=2, B) = 512 blocks, 256 threads (4 waves).
// Wave w: S rows 16w..16w+15; PV channels c_local = 32w..32w+31.
// ---------------------------------------------------------------------------
__global__ __launch_bounds__(256) void attn(
    const float* __restrict__ x, const short* __restrict__ q_t,
    const short* __restrict__ k_t, const short* __restrict__ v_b,
    const float* __restrict__ gamma, float* __restrict__ out) {
    __shared__ alignas(16) short q_s[64 * 32];   // [i][d]   4 KB
    __shared__ alignas(16) short k_s[64 * 32];   // [j][d]   4 KB
    __shared__ alignas(16) short v_s[128 * 64];  // [c][slot] 16 KB (xor-swizzled j8)
    __shared__ alignas(16) float s_s[64 * 68];   // S tile fp32, 17.4 KB
    __shared__ alignas(16) short p_s[64 * 72];   // P tile bf16, 9.2 KB
    __shared__ float alpha_s[64];
    __shared__ float l_s[64];

    const int b = blockIdx.z, cg = blockIdx.y;
    const int i0 = blockIdx.x * 64;
    const int tid = threadIdx.x;
    const int w = tid >> 6, lane = tid & 63;
    const int qd = lane >> 4, m = lane & 15;
    const int r = tid >> 2, qt4 = tid & 3;       // softmax: 4 threads per row

    // stage Q once (4 KB contiguous in q_t)
    load_lds16(q_t + ((size_t)b * Nn + i0) * Dd + tid * 8, q_s + tid * 8);

    const short* ktb = k_t + (size_t)b * Nn * Dd;
    const short* vtb = v_b + ((size_t)(b * Cc) + cg * CH) * Nn;

    f32x4 oacc[4][2];
#pragma unroll
    for (int mt = 0; mt < 4; ++mt)
#pragma unroll
        for (int nt = 0; nt < 2; ++nt) oacc[mt][nt] = (f32x4){0.f, 0.f, 0.f, 0.f};

    float m_i = -3e38f, l_i = 0.f;

    for (int jt = 0; jt < Nn / 64; ++jt) {
        const int j0 = jt * 64;
        __syncthreads();   // prior-iteration v_s/p_s reads complete

        // stage K tile (contiguous 4 KB) + V tile (16 KB, xor-swizzled)
        load_lds16(ktb + (size_t)j0 * Dd + tid * 8, k_s + tid * 8);
#pragma unroll
        for (int p = 0; p < 4; ++p) {
            const int cl = 32 * p + (tid >> 3);
            const int j8 = (tid & 7) ^ (cl & 7);
            load_lds16(vtb + (size_t)cl * Nn + j0 + j8 * 8, v_s + 2048 * p + tid * 8);
        }
        __syncthreads();   // staging drained (vmcnt before barrier)

        // ---- S = Q K^T : wave w does m-tile w, all 4 n-tiles ----
        const bf16x8 af = *(const bf16x8*)(q_s + (16 * w + m) * Dd + 8 * qd);
        f32x4 sf[4];
#pragma unroll
        for (int nt = 0; nt < 4; ++nt) {
            const bf16x8 bf = *(const bf16x8*)(k_s + (16 * nt + m) * Dd + 8 * qd);
            sf[nt] = __builtin_amdgcn_mfma_f32_16x16x32_bf16(
                af, bf, (f32x4){0.f, 0.f, 0.f, 0.f}, 0, 0, 0);
        }
#pragma unroll
        for (int nt = 0; nt < 4; ++nt)
#pragma unroll
            for (int rr = 0; rr < 4; ++rr)
                s_s[(16 * w + 4 * qd + rr) * 68 + 16 * nt + m] = sf[nt][rr];
        __syncthreads();

        // ---- online softmax: 256 threads, 4 per row, 16 cols each ----
        {
            const float* rowp = s_s + r * 68 + qt4 * 16;
            float ev[16];
            float tmax = -3e38f;
#pragma unroll
            for (int e4 = 0; e4 < 4; ++e4) {
                const f32x4 vv = ((const f32x4*)rowp)[e4];
                ev[4*e4+0] = vv[0]; ev[4*e4+1] = vv[1];
                ev[4*e4+2] = vv[2]; ev[4*e4+3] = vv[3];
                tmax = fmaxf(tmax, fmaxf(fmaxf(vv[0], vv[1]), fmaxf(vv[2], vv[3])));
            }
            tmax = fmaxf(tmax, __shfl_xor(tmax, 1, 64));
            tmax = fmaxf(tmax, __shfl_xor(tmax, 2, 64));
            const float mnew = fmaxf(m_i, tmax);
            const float al = __expf(m_i - mnew);
            float psum = 0.f;
#pragma unroll
            for (int e = 0; e < 16; ++e) {
                ev[e] = __expf(ev[e] - mnew);
                psum += ev[e];
            }
            psum += __shfl_xor(psum, 1, 64);
            psum += __shfl_xor(psum, 2, 64);
            l_i = al * l_i + psum;
            m_i = mnew;
            if (qt4 == 0) alpha_s[r] = al;
            unsigned u[8];
#pragma unroll
            for (int h = 0; h < 8; ++h) u[h] = pk2(ev[2*h], ev[2*h+1]);
            uint4* pd = (uint4*)(p_s + r * 72 + qt4 * 16);
            pd[0] = make_uint4(u[0], u[1], u[2], u[3]);
            pd[1] = make_uint4(u[4], u[5], u[6], u[7]);
        }
        __syncthreads();

        // ---- PV: rescale O by alpha, then O += P * V^T ----
#pragma unroll
        for (int mt = 0; mt < 4; ++mt)
#pragma unroll
            for (int rr = 0; rr < 4; ++rr) {
                const float a_ = alpha_s[16 * mt + 4 * qd + rr];
                oacc[mt][0][rr] *= a_;
                oacc[mt][1][rr] *= a_;
            }
#pragma unroll
        for (int kc = 0; kc < 2; ++kc) {
            bf16x8 pa[4];
#pragma unroll
            for (int mt = 0; mt < 4; ++mt)
                pa[mt] = *(const bf16x8*)(p_s + (16 * mt + m) * 72 + 32 * kc + 8 * qd);
#pragma unroll
            for (int nt = 0; nt < 2; ++nt) {
                const int cl = 32 * w + 16 * nt + m;
                const bf16x8 vb8 = *(const bf16x8*)(
                    v_s + cl * 64 + (((qd + 4 * kc) ^ (cl & 7)) * 8));
#pragma unroll
                for (int mt = 0; mt < 4; ++mt)
                    oacc[mt][nt] = __builtin_amdgcn_mfma_f32_16x16x32_bf16(
                        pa[mt], vb8, oacc[mt][nt], 0, 0, 0);
            }
        }
    }

    if (qt4 == 0) l_s[r] = l_i;

    // ---- epilogue: transpose O through LDS, out = gamma*O/l + x ----
    const float g = gamma[0];
#pragma unroll
    for (int ntp = 0; ntp < 2; ++ntp) {
        __syncthreads();
#pragma unroll
        for (int mt = 0; mt < 4; ++mt)
#pragma unroll
            for (int rr = 0; rr < 4; ++rr)
                s_s[(16 * mt + 4 * qd + rr) * 68 + 16 * w + m] = oacc[mt][ntp][rr];
        __syncthreads();
        const int i = lane;
        const float linv = 1.0f / l_s[i];
#pragma unroll
        for (int kk = 0; kk < 16; ++kk) {
            const int cp = w * 16 + kk;
            const int c = cg * CH + 32 * w + 16 * ntp + kk;
            const float val = s_s[i * 68 + cp] * linv;
            const size_t gidx = ((size_t)b * Cc + c) * Nn + i0 + i;
            out[gidx] = g * val + x[gidx];
        }
    }
}

// ---------------------------------------------------------------------------
extern "C" void kernel_launch(void* const* d_in, const int* in_sizes, int n_in,
                              void* d_out, int out_size, void* d_ws, size_t ws_size,
                              hipStream_t stream) {
    const float* x     = (const float*)d_in[0];
    const float* qw    = (const float*)d_in[1];
    const float* kw    = (const float*)d_in[2];
    const float* vw    = (const float*)d_in[3];
    const float* gamma = (const float*)d_in[4];
    float* out = (float*)d_out;

    short* q_t = (short*)d_ws;                       // [b][n][32] bf16, 1 MB
    short* k_t = q_t + (size_t)Bb * Nn * Dd;         // [b][n][32] bf16, 1 MB
    short* v_b = k_t + (size_t)Bb * Nn * Dd;         // [b][c][n]  bf16, 8.4 MB

    qkv_proj<<<dim3(4, 20, Bb), 256, 0, stream>>>(x, qw, kw, vw, q_t, k_t, v_b);
    attn<<<dim3(Nn / 64, Cc / CH, Bb), 256, 0, stream>>>(x, q_t, k_t, v_b,
                                                         gamma, out);
}